// Round 12
// baseline (4415.664 us; speedup 1.0000x reference)
//
#include <hip/hip_runtime.h>
#include <math.h>

// ---------------------------------------------------------------------------
// RNN_48558900248904. Round 12 = R10 (best, 1158us) + two residue cuts,
// schedule otherwise byte-identical:
//  (1) h1-defer: single h1 buffer; P2(t) keeps h1(t) in 8 VGPRs; predicated
//      LDS write at P1(t+1) top (2 barriers before next reader P2(t+1)).
//      Removes oldv-read + select path of the ping-pong.
//  (2) x2 parity unroll (template<int P>): weight bases become compile-time
//      -> SGPR+imm addressing, no per-step parity ternaries.
// R11 lesson folded in: weights stay global->register (deep prefetch); LDS
// staging of the weight stream puts ds_read latency on the critical path.
// ---------------------------------------------------------------------------

typedef __attribute__((ext_vector_type(8))) short bf16x8;   // 8 bf16 (4 VGPRs)
typedef __attribute__((ext_vector_type(4))) short s16x4;    // 8B store
typedef __attribute__((ext_vector_type(4))) float f32x4;

#define MFMA(a, b, c) __builtin_amdgcn_mfma_f32_16x16x32_bf16((a), (b), (c), 0, 0, 0)

#define T_  200

// ws layout (shorts)
#define WLP_OFF   0                       // Wl packed: ((mt*5+kk)*64+lane)*8
#define WIHP_OFF  40960                   // 4 mats x 65536
#define WHHP_OFF  (40960 + 262144)
#define BSUM_BYTE_OFF ((40960 + 262144 + 262144) * 2)   // then [2][2][256] f32

// LDS layout (shorts)
#define XCS 168
#define HS  264
#define SM_XCAT 0                         // [32][168] = 5376
#define SM_XPJ  5376                      // [32][264] = 8448
#define SM_H0   (5376 + 8448)             // 13824
#define SM_H1   (13824 + 8448)            // 22272
#define SM_BIAS (22272 + 8448)            // 30720 : 1280 f32 = 2560 shorts
#define SM_TOT  (30720 + 2560)            // 33280 shorts = 66560 B

__device__ __forceinline__ short f2bf(float f) {
    unsigned u = __float_as_uint(f);
    u += 0x7fffu + ((u >> 16) & 1u);      // RNE
    return (short)(u >> 16);
}
__device__ __forceinline__ float bf2f(short s) {
    return __uint_as_float(((unsigned)(unsigned short)s) << 16);
}
__device__ __forceinline__ float tanh_fast(float x) {
    float e = __builtin_amdgcn_exp2f(x * 2.88539008f);
    return 1.0f - 2.0f * __builtin_amdgcn_rcpf(e + 1.0f);
}

// ---------------------------------------------------------------------------
__global__ void prep_kernel(const float* __restrict__ Wl,
                            const float* __restrict__ Wih,
                            const float* __restrict__ Whh,
                            const float* __restrict__ bih,
                            const float* __restrict__ bhh,
                            short* __restrict__ wsS,
                            float* __restrict__ bsum) {
    int tid = blockIdx.x * 256 + threadIdx.x;
    if (tid < 5120) {                       // Wl pack (K padded 136 -> 160)
        int mt = tid / 320, rem = tid % 320;
        int kk = rem / 64, lane = rem % 64;
        int o = mt * 16 + (lane & 15);
        int kb = kk * 32 + (lane >> 4) * 8;
        short* dst = wsS + WLP_OFF + tid * 8;
#pragma unroll
        for (int e = 0; e < 8; e++) {
            int k = kb + e;
            dst[e] = f2bf((k < 136) ? Wl[o * 136 + k] : 0.0f);
        }
    } else if (tid < 5120 + 32768) {        // Wih pack
        int jj = tid - 5120;
        int mat = jj / 8192, rem = jj % 8192;
        int lane = rem & 63, kk = (rem >> 6) & 7, mt = rem >> 9;
        int o = mt * 16 + (lane & 15);
        int kb = kk * 32 + (lane >> 4) * 8;
        const float* src = Wih + (mat * 256 + o) * 256;
        short* dst = wsS + WIHP_OFF + mat * 65536 + rem * 8;
#pragma unroll
        for (int e = 0; e < 8; e++) dst[e] = f2bf(src[kb + e]);
    } else if (tid < 5120 + 65536) {        // Whh pack
        int jj = tid - 37888;
        int mat = jj / 8192, rem = jj % 8192;
        int lane = rem & 63, kk = (rem >> 6) & 7, mt = rem >> 9;
        int o = mt * 16 + (lane & 15);
        int kb = kk * 32 + (lane >> 4) * 8;
        const float* src = Whh + (mat * 256 + o) * 256;
        short* dst = wsS + WHHP_OFF + mat * 65536 + rem * 8;
#pragma unroll
        for (int e = 0; e < 8; e++) dst[e] = f2bf(src[kb + e]);
    } else if (tid < 5120 + 65536 + 1024) { // bsum = bih + bhh
        int j = tid - 70656;
        bsum[j] = bih[j] + bhh[j];
    }
}

// ---------------------------------------------------------------------------
struct GReg { f32x4 e0, e1, dv; };

__device__ __forceinline__ void gather_load(GReg& g, const float* __restrict__ dense,
                                            const int* __restrict__ sparse,
                                            const float* __restrict__ emb,
                                            int b0, int tt, int tid) {
    int gs = tid >> 4, gf = (tid >> 2) & 3, gq = tid & 3;
    int ix = sparse[(b0 + gs) * (T_ * 4) + tt * 4 + gf];
    const float* ep = emb + gf * 32000 + ix * 32 + gq * 8;
    g.e0 = *(const f32x4*)ep;
    g.e1 = *(const f32x4*)(ep + 4);
    if (tid < 64)
        g.dv = *(const f32x4*)(dense + (b0 + (tid >> 1)) * (T_ * 8) + tt * 8 + (tid & 1) * 4);
}
__device__ __forceinline__ void gather_commit(const GReg& g, short* __restrict__ buf, int tid) {
    int gs = tid >> 4, gf = (tid >> 2) & 3, gq = tid & 3;
    s16x4 w0, w1;
#pragma unroll
    for (int r = 0; r < 4; r++) { w0[r] = f2bf(g.e0[r]); w1[r] = f2bf(g.e1[r]); }
    int off = gs * XCS + 8 + gf * 32 + gq * 8;
    *(s16x4*)(buf + off) = w0;
    *(s16x4*)(buf + off + 4) = w1;
    if (tid < 64) {
        s16x4 wd;
#pragma unroll
        for (int r = 0; r < 4; r++) wd[r] = f2bf(g.dv[r]);
        *(s16x4*)(buf + (tid >> 1) * XCS + (tid & 1) * 4) = wd;
    }
}

// weight chunk loaders (slot indices constant after unroll -> registers)
__device__ __forceinline__ void load_c4(bf16x8 (&d)[4], const short* A, const short* B,
                                        int kk, int wid, int lane) {
    d[0] = *(const bf16x8*)(A + (((wid * 2 + 0) * 8 + kk) * 64 + lane) * 8);
    d[1] = *(const bf16x8*)(A + (((wid * 2 + 1) * 8 + kk) * 64 + lane) * 8);
    d[2] = *(const bf16x8*)(B + (((wid * 2 + 0) * 8 + kk) * 64 + lane) * 8);
    d[3] = *(const bf16x8*)(B + (((wid * 2 + 1) * 8 + kk) * 64 + lane) * 8);
}
__device__ __forceinline__ void load_wl2(bf16x8& d0, bf16x8& d1,
                                         const short* Wlp, int kk, int wid, int lane) {
    d0 = *(const bf16x8*)(Wlp + (((wid * 2 + 0) * 5 + kk) * 64 + lane) * 8);
    d1 = *(const bf16x8*)(Wlp + (((wid * 2 + 1) * 5 + kk) * 64 + lane) * 8);
}

// ---------------------------------------------------------------------------
// One step, compile-time parity P. Schedule identical to R10; h1 deferred.
template<int P>
__device__ __forceinline__ void rnn_step(
    int t, bool hasNext,
    const float* __restrict__ dense, const int* __restrict__ sparse,
    const float* __restrict__ emb, const short* __restrict__ wsS,
    const float* __restrict__ blS,
    short* __restrict__ xcat, short* __restrict__ xpj,
    short* __restrict__ h0p, short* __restrict__ h1p,
    bf16x8 (&wa)[3][4], bf16x8 (&wnext)[4], bf16x8 (&hreg0)[2][8],
    s16x4 (&h1def)[2][2], GReg& g,
    int lane, int lrow, int lgrp, int wid, int len0, int len1, int b0, int tid)
{
    const short* Aih1 = wsS + WIHP_OFF + P * 65536;
    const short* Ahh1 = wsS + WHHP_OFF + P * 65536;
    const short* Aih2 = wsS + WIHP_OFF + (2 + P) * 65536;
    const short* Ahh2 = wsS + WHHP_OFF + (2 + P) * 65536;
    const short* AihN = wsS + WIHP_OFF + (P ^ 1) * 65536;
    const short* AhhN = wsS + WHHP_OFF + (P ^ 1) * 65536;
    const short* Wlp  = wsS + WLP_OFF;

    f32x4 acc[2][2];

    // deferred h1(t-1) LDS write (next reader = P2(t), after b1)
    if (t > 0) {
#pragma unroll
        for (int mt = 0; mt < 2; mt++) {
            int o0 = wid * 32 + mt * 16 + lgrp * 4;
#pragma unroll
            for (int nt = 0; nt < 2; nt++) {
                int len = nt ? len1 : len0;
                if (t - 1 < len)
                    *(s16x4*)(h1p + (nt * 16 + lrow) * HS + o0) = h1def[mt][nt];
            }
        }
    }

    // ================= P1: layer0(t) =================
#pragma unroll
    for (int mt = 0; mt < 2; mt++) {
        f32x4 bi = *(const f32x4*)(blS + 256 + P * 256 + wid * 32 + mt * 16 + lgrp * 4);
        acc[mt][0] = bi; acc[mt][1] = bi;
    }
#pragma unroll
    for (int kk = 0; kk < 8; kk++) {
        if (kk <= 5)      load_c4(wa[(kk + 2) % 3], Aih1, Ahh1, kk + 2, wid, lane);
        else if (kk == 6) load_c4(wnext, Aih2, Ahh2, 0, wid, lane);
        else              load_c4(wa[2], Aih2, Ahh2, 1, wid, lane);
        const int s = kk % 3;
        bf16x8 bxf[2];
#pragma unroll
        for (int nt = 0; nt < 2; nt++)
            bxf[nt] = *(const bf16x8*)(xpj + (nt * 16 + lrow) * HS + kk * 32 + lgrp * 8);
#pragma unroll
        for (int mt = 0; mt < 2; mt++)
#pragma unroll
            for (int nt = 0; nt < 2; nt++) {
                acc[mt][nt] = MFMA(wa[s][mt], bxf[nt], acc[mt][nt]);
                acc[mt][nt] = MFMA(wa[s][2 + mt], hreg0[nt][kk], acc[mt][nt]);
            }
    }
#pragma unroll
    for (int mt = 0; mt < 2; mt++) {        // in-place predicated h0 write
        int o0 = wid * 32 + mt * 16 + lgrp * 4;
#pragma unroll
        for (int nt = 0; nt < 2; nt++) {
            s16x4 w;
#pragma unroll
            for (int r = 0; r < 4; r++) w[r] = f2bf(tanh_fast(acc[mt][nt][r]));
            int len = nt ? len1 : len0;
            if (t < len)
                *(s16x4*)(h0p + (nt * 16 + lrow) * HS + o0) = w;
        }
    }
    if (hasNext) gather_commit(g, xcat, tid);   // g issued at (t-1)'s A-tail
    __syncthreads();   // b1: h0(t), h1(t-1), xcat(t+1) visible

    // ================= P2: layer1(t) =================
#pragma unroll
    for (int mt = 0; mt < 2; mt++) {
        f32x4 bi = *(const f32x4*)(blS + 256 + (2 + P) * 256 + wid * 32 + mt * 16 + lgrp * 4);
        acc[mt][0] = bi; acc[mt][1] = bi;
    }
#pragma unroll
    for (int kk = 0; kk < 8; kk++) {
        if (kk <= 5)      load_c4(wa[kk % 3], Aih2, Ahh2, kk + 2, wid, lane);
        else if (kk == 6) { if (hasNext) load_wl2(wnext[0], wnext[1], Wlp, 0, wid, lane); }
        else              { if (hasNext) load_wl2(wnext[2], wnext[3], Wlp, 1, wid, lane); }
        bf16x8 bhf[2];
#pragma unroll
        for (int nt = 0; nt < 2; nt++) {    // fresh h0: ih operand + next P1 hh
            hreg0[nt][kk] = *(const bf16x8*)(h0p + (nt * 16 + lrow) * HS + kk * 32 + lgrp * 8);
            bhf[nt] = *(const bf16x8*)(h1p + (nt * 16 + lrow) * HS + kk * 32 + lgrp * 8);
        }
        if (kk == 0) {
#pragma unroll
            for (int mt = 0; mt < 2; mt++)
#pragma unroll
                for (int nt = 0; nt < 2; nt++) {
                    acc[mt][nt] = MFMA(wnext[mt], hreg0[nt][0], acc[mt][nt]);
                    acc[mt][nt] = MFMA(wnext[2 + mt], bhf[nt], acc[mt][nt]);
                }
        } else {
            const int s = (kk + 1) % 3;
#pragma unroll
            for (int mt = 0; mt < 2; mt++)
#pragma unroll
                for (int nt = 0; nt < 2; nt++) {
                    acc[mt][nt] = MFMA(wa[s][mt], hreg0[nt][kk], acc[mt][nt]);
                    acc[mt][nt] = MFMA(wa[s][2 + mt], bhf[nt], acc[mt][nt]);
                }
        }
    }
#pragma unroll
    for (int mt = 0; mt < 2; mt++)           // h1(t) -> registers (deferred)
#pragma unroll
        for (int nt = 0; nt < 2; nt++) {
            s16x4 w;
#pragma unroll
            for (int r = 0; r < 4; r++) w[r] = f2bf(tanh_fast(acc[mt][nt][r]));
            h1def[mt][nt] = w;
        }

    // ================= A: xproj(t+1) =================
    if (hasNext) {
#pragma unroll
        for (int mt = 0; mt < 2; mt++) {
            f32x4 bi = *(const f32x4*)(blS + wid * 32 + mt * 16 + lgrp * 4);
            acc[mt][0] = bi; acc[mt][1] = bi;
        }
#pragma unroll
        for (int kk = 0; kk < 5; kk++) {
            if (kk <= 2)      load_wl2(wa[kk][0], wa[kk][1], Wlp, kk + 2, wid, lane);
            else if (kk == 3) load_c4(wa[0], AihN, AhhN, 0, wid, lane);
            else              load_c4(wa[1], AihN, AhhN, 1, wid, lane);
            bf16x8 w0, w1;
            if (kk == 0)      { w0 = wnext[0]; w1 = wnext[1]; }
            else if (kk == 1) { w0 = wnext[2]; w1 = wnext[3]; }
            else              { w0 = wa[kk - 2][0]; w1 = wa[kk - 2][1]; }
            bf16x8 bxf[2];
#pragma unroll
            for (int nt = 0; nt < 2; nt++)
                bxf[nt] = *(const bf16x8*)(xcat + (nt * 16 + lrow) * XCS + kk * 32 + lgrp * 8);
#pragma unroll
            for (int nt = 0; nt < 2; nt++) {
                acc[0][nt] = MFMA(w0, bxf[nt], acc[0][nt]);
                acc[1][nt] = MFMA(w1, bxf[nt], acc[1][nt]);
            }
        }
#pragma unroll
        for (int mt = 0; mt < 2; mt++) {
            int o0 = wid * 32 + mt * 16 + lgrp * 4;
#pragma unroll
            for (int nt = 0; nt < 2; nt++) {
                s16x4 w;
#pragma unroll
                for (int r = 0; r < 4; r++) w[r] = f2bf(fmaxf(acc[mt][nt][r], 0.0f));
                *(s16x4*)(xpj + (nt * 16 + lrow) * HS + o0) = w;
            }
        }
        if (t + 2 < T_)                       // gather for t+2, issued LAST
            gather_load(g, dense, sparse, emb, b0, t + 2, tid);
    }
    __syncthreads();   // b2: h1def pending; xpj(t+1) visible; prefetch in flight
}

// ---------------------------------------------------------------------------
__global__ __launch_bounds__(512, 1) void rnn_kernel(
    const float* __restrict__ dense, const int* __restrict__ sparse,
    const int* __restrict__ lengths, const float* __restrict__ emb,
    const float* __restrict__ bl, const float* __restrict__ Wout,
    const float* __restrict__ bout, const short* __restrict__ wsS,
    const float* __restrict__ bsum, float* __restrict__ out) {
    __shared__ alignas(16) short sm[SM_TOT];
    short* xcat = sm + SM_XCAT;
    short* xpj  = sm + SM_XPJ;
    short* h0p  = sm + SM_H0;
    short* h1p  = sm + SM_H1;
    float* blS  = (float*)(sm + SM_BIAS);

    const int tid  = threadIdx.x;
    const int wid  = tid >> 6;
    const int lane = tid & 63;
    const int lrow = lane & 15;
    const int lgrp = lane >> 4;
    const int b0   = blockIdx.x * 32;
    const short* Wlp = wsS + WLP_OFF;

    for (int i = tid; i < SM_BIAS; i += 512) sm[i] = 0;
    for (int i = tid; i < 1280; i += 512)
        blS[i] = (i < 256) ? bl[i] : bsum[i - 256];

    const int len0 = lengths[b0 + lrow];
    const int len1 = lengths[b0 + 16 + lrow];

    __syncthreads();
    { GReg g0; gather_load(g0, dense, sparse, emb, b0, 0, tid); gather_commit(g0, xcat, tid); }
    __syncthreads();

    // xproj(0): direct-load version (runs once)
    {
        f32x4 xacc[2][2];
#pragma unroll
        for (int mt = 0; mt < 2; mt++) {
            f32x4 bi = *(const f32x4*)(blS + wid * 32 + mt * 16 + lgrp * 4);
            xacc[mt][0] = bi; xacc[mt][1] = bi;
        }
#pragma unroll
        for (int kk = 0; kk < 5; kk++) {
            bf16x8 wl0, wl1;
            load_wl2(wl0, wl1, Wlp, kk, wid, lane);
            bf16x8 bxf[2];
#pragma unroll
            for (int nt = 0; nt < 2; nt++)
                bxf[nt] = *(const bf16x8*)(xcat + (nt * 16 + lrow) * XCS + kk * 32 + lgrp * 8);
#pragma unroll
            for (int nt = 0; nt < 2; nt++) {
                xacc[0][nt] = MFMA(wl0, bxf[nt], xacc[0][nt]);
                xacc[1][nt] = MFMA(wl1, bxf[nt], xacc[1][nt]);
            }
        }
#pragma unroll
        for (int mt = 0; mt < 2; mt++) {
            int o0 = wid * 32 + mt * 16 + lgrp * 4;
#pragma unroll
            for (int nt = 0; nt < 2; nt++) {
                s16x4 w;
#pragma unroll
                for (int r = 0; r < 4; r++) w[r] = f2bf(fmaxf(xacc[mt][nt][r], 0.0f));
                *(s16x4*)(xpj + (nt * 16 + lrow) * HS + o0) = w;
            }
        }
    }

    bf16x8 wa[3][4];                // rolling weight window
    bf16x8 wnext[4];                // cross-phase prefetch buffer
    bf16x8 hreg0[2][8];             // h0(-1) = 0
    s16x4  h1def[2][2];             // deferred h1 values
#pragma unroll
    for (int nt = 0; nt < 2; nt++)
#pragma unroll
        for (int kk = 0; kk < 8; kk++) {
            bf16x8 z;
#pragma unroll
            for (int e = 0; e < 8; e++) z[e] = 0;
            hreg0[nt][kk] = z;
        }
#pragma unroll
    for (int mt = 0; mt < 2; mt++)
#pragma unroll
        for (int nt = 0; nt < 2; nt++) { s16x4 z; z[0]=z[1]=z[2]=z[3]=0; h1def[mt][nt] = z; }

    // bootstrap: P1(t=0, p=0) chunks c0,c1; then gather(t=1)
    load_c4(wa[0], wsS + WIHP_OFF, wsS + WHHP_OFF, 0, wid, lane);
    load_c4(wa[1], wsS + WIHP_OFF, wsS + WHHP_OFF, 1, wid, lane);
    GReg g;
    gather_load(g, dense, sparse, emb, b0, 1, tid);
    __syncthreads();               // xpj(0) visible

    for (int tb = 0; tb < T_; tb += 2) {
        rnn_step<0>(tb, true, dense, sparse, emb, wsS, blS, xcat, xpj, h0p, h1p,
                    wa, wnext, hreg0, h1def, g,
                    lane, lrow, lgrp, wid, len0, len1, b0, tid);
        rnn_step<1>(tb + 1, tb + 1 < T_ - 1, dense, sparse, emb, wsS, blS,
                    xcat, xpj, h0p, h1p, wa, wnext, hreg0, h1def, g,
                    lane, lrow, lgrp, wid, len0, len1, b0, tid);
    }

    // flush h1(T-1), then epilogue
#pragma unroll
    for (int mt = 0; mt < 2; mt++) {
        int o0 = wid * 32 + mt * 16 + lgrp * 4;
#pragma unroll
        for (int nt = 0; nt < 2; nt++) {
            int len = nt ? len1 : len0;
            if (T_ - 1 < len)
                *(s16x4*)(h1p + (nt * 16 + lrow) * HS + o0) = h1def[mt][nt];
        }
    }
    __syncthreads();

    // ---- epilogue: out = sigmoid(h1 . Wout + bout)
    float* red = (float*)(sm + SM_XPJ);
    if (tid < 256) {
        int s = tid >> 3, part = tid & 7;
        const short* hr = h1p + s * HS + part * 32;
        float sum = 0.0f;
#pragma unroll
        for (int k = 0; k < 32; k++) sum += bf2f(hr[k]) * Wout[part * 32 + k];
        red[s * 8 + part] = sum;
    }
    __syncthreads();
    if (tid < 32) {
        float x = bout[0];
#pragma unroll
        for (int i = 0; i < 8; i++) x += red[tid * 8 + i];
        float e = __builtin_amdgcn_exp2f(x * 1.44269504f);
        out[b0 + tid] = 1.0f - __builtin_amdgcn_rcpf(1.0f + e);
    }
}

// ---------------------------------------------------------------------------
extern "C" void kernel_launch(void* const* d_in, const int* in_sizes, int n_in,
                              void* d_out, int out_size, void* d_ws, size_t ws_size,
                              hipStream_t stream) {
    const float* dense   = (const float*)d_in[0];
    const int*   sparse  = (const int*)d_in[1];
    const int*   lengths = (const int*)d_in[2];
    const float* emb     = (const float*)d_in[3];
    const float* Wl      = (const float*)d_in[4];
    const float* bl      = (const float*)d_in[5];
    const float* Wih     = (const float*)d_in[6];
    const float* Whh     = (const float*)d_in[7];
    const float* bih     = (const float*)d_in[8];
    const float* bhh     = (const float*)d_in[9];
    const float* Wout    = (const float*)d_in[10];
    const float* bout    = (const float*)d_in[11];

    short* wsS  = (short*)d_ws;
    float* bsum = (float*)((char*)d_ws + BSUM_BYTE_OFF);

    prep_kernel<<<280, 256, 0, stream>>>(Wl, Wih, Whh, bih, bhh, wsS, bsum);
    rnn_kernel<<<256, 512, 0, stream>>>(dense, sparse, lengths, emb, bl, Wout, bout,
                                        wsS, bsum, (float*)d_out);
}

// Round 13
// 1258.374 us; speedup vs baseline: 3.5090x; 3.5090x over previous
//
#include <hip/hip_runtime.h>
#include <math.h>

// ---------------------------------------------------------------------------
// RNN_48558900248904. Round 13 = R10 (1158us, best verified schedule) +
// h1-defer ONLY (the R11 component proven safe: rolled loop, VGPR 104):
//   single h1 buffer; P2(t) keeps h1(t) in 8 VGPRs; predicated LDS write at
//   the top of step t+1 (two barriers before next reader P2(t+1)); flush
//   after the loop. Removes the ping-pong oldv-read + select path.
// R12 lesson (4th spill confirmation): t-loop body MUST stay a single rolled
// step — template step-unrolling stretches live ranges past the 128-VGPR cap
// (fatal spill -> L2 thrash). Runtime parity, issue map, gather placement
// byte-identical to R10.
// ---------------------------------------------------------------------------

typedef __attribute__((ext_vector_type(8))) short bf16x8;   // 8 bf16 (4 VGPRs)
typedef __attribute__((ext_vector_type(4))) short s16x4;    // 8B store
typedef __attribute__((ext_vector_type(4))) float f32x4;

#define MFMA(a, b, c) __builtin_amdgcn_mfma_f32_16x16x32_bf16((a), (b), (c), 0, 0, 0)

#define T_  200

// ws layout (shorts)
#define WLP_OFF   0                       // Wl packed: ((mt*5+kk)*64+lane)*8
#define WIHP_OFF  40960                   // 4 mats x 65536
#define WHHP_OFF  (40960 + 262144)
#define BSUM_BYTE_OFF ((40960 + 262144 + 262144) * 2)   // then [2][2][256] f32

// LDS layout (shorts)
#define XCS 168
#define HS  264
#define SM_XCAT 0                         // [32][168] = 5376
#define SM_XPJ  5376                      // [32][264] = 8448
#define SM_H0   (5376 + 8448)             // 13824
#define SM_H1   (13824 + 8448)            // 22272
#define SM_BIAS (22272 + 8448)            // 30720 : 1280 f32 = 2560 shorts
#define SM_TOT  (30720 + 2560)            // 33280 shorts = 66560 B

__device__ __forceinline__ short f2bf(float f) {
    unsigned u = __float_as_uint(f);
    u += 0x7fffu + ((u >> 16) & 1u);      // RNE
    return (short)(u >> 16);
}
__device__ __forceinline__ float bf2f(short s) {
    return __uint_as_float(((unsigned)(unsigned short)s) << 16);
}
__device__ __forceinline__ float tanh_fast(float x) {
    float e = __builtin_amdgcn_exp2f(x * 2.88539008f);
    return 1.0f - 2.0f * __builtin_amdgcn_rcpf(e + 1.0f);
}

// ---------------------------------------------------------------------------
__global__ void prep_kernel(const float* __restrict__ Wl,
                            const float* __restrict__ Wih,
                            const float* __restrict__ Whh,
                            const float* __restrict__ bih,
                            const float* __restrict__ bhh,
                            short* __restrict__ wsS,
                            float* __restrict__ bsum) {
    int tid = blockIdx.x * 256 + threadIdx.x;
    if (tid < 5120) {                       // Wl pack (K padded 136 -> 160)
        int mt = tid / 320, rem = tid % 320;
        int kk = rem / 64, lane = rem % 64;
        int o = mt * 16 + (lane & 15);
        int kb = kk * 32 + (lane >> 4) * 8;
        short* dst = wsS + WLP_OFF + tid * 8;
#pragma unroll
        for (int e = 0; e < 8; e++) {
            int k = kb + e;
            dst[e] = f2bf((k < 136) ? Wl[o * 136 + k] : 0.0f);
        }
    } else if (tid < 5120 + 32768) {        // Wih pack
        int jj = tid - 5120;
        int mat = jj / 8192, rem = jj % 8192;
        int lane = rem & 63, kk = (rem >> 6) & 7, mt = rem >> 9;
        int o = mt * 16 + (lane & 15);
        int kb = kk * 32 + (lane >> 4) * 8;
        const float* src = Wih + (mat * 256 + o) * 256;
        short* dst = wsS + WIHP_OFF + mat * 65536 + rem * 8;
#pragma unroll
        for (int e = 0; e < 8; e++) dst[e] = f2bf(src[kb + e]);
    } else if (tid < 5120 + 65536) {        // Whh pack
        int jj = tid - 37888;
        int mat = jj / 8192, rem = jj % 8192;
        int lane = rem & 63, kk = (rem >> 6) & 7, mt = rem >> 9;
        int o = mt * 16 + (lane & 15);
        int kb = kk * 32 + (lane >> 4) * 8;
        const float* src = Whh + (mat * 256 + o) * 256;
        short* dst = wsS + WHHP_OFF + mat * 65536 + rem * 8;
#pragma unroll
        for (int e = 0; e < 8; e++) dst[e] = f2bf(src[kb + e]);
    } else if (tid < 5120 + 65536 + 1024) { // bsum = bih + bhh
        int j = tid - 70656;
        bsum[j] = bih[j] + bhh[j];
    }
}

// ---------------------------------------------------------------------------
struct GReg { f32x4 e0, e1, dv; };

__device__ __forceinline__ void gather_load(GReg& g, const float* __restrict__ dense,
                                            const int* __restrict__ sparse,
                                            const float* __restrict__ emb,
                                            int b0, int tt, int tid) {
    int gs = tid >> 4, gf = (tid >> 2) & 3, gq = tid & 3;
    int ix = sparse[(b0 + gs) * (T_ * 4) + tt * 4 + gf];
    const float* ep = emb + gf * 32000 + ix * 32 + gq * 8;
    g.e0 = *(const f32x4*)ep;
    g.e1 = *(const f32x4*)(ep + 4);
    if (tid < 64)
        g.dv = *(const f32x4*)(dense + (b0 + (tid >> 1)) * (T_ * 8) + tt * 8 + (tid & 1) * 4);
}
__device__ __forceinline__ void gather_commit(const GReg& g, short* __restrict__ buf, int tid) {
    int gs = tid >> 4, gf = (tid >> 2) & 3, gq = tid & 3;
    s16x4 w0, w1;
#pragma unroll
    for (int r = 0; r < 4; r++) { w0[r] = f2bf(g.e0[r]); w1[r] = f2bf(g.e1[r]); }
    int off = gs * XCS + 8 + gf * 32 + gq * 8;
    *(s16x4*)(buf + off) = w0;
    *(s16x4*)(buf + off + 4) = w1;
    if (tid < 64) {
        s16x4 wd;
#pragma unroll
        for (int r = 0; r < 4; r++) wd[r] = f2bf(g.dv[r]);
        *(s16x4*)(buf + (tid >> 1) * XCS + (tid & 1) * 4) = wd;
    }
}

// weight chunk loaders (slot indices constant after unroll -> registers)
__device__ __forceinline__ void load_c4(bf16x8 (&d)[4], const short* A, const short* B,
                                        int kk, int wid, int lane) {
    d[0] = *(const bf16x8*)(A + (((wid * 2 + 0) * 8 + kk) * 64 + lane) * 8);
    d[1] = *(const bf16x8*)(A + (((wid * 2 + 1) * 8 + kk) * 64 + lane) * 8);
    d[2] = *(const bf16x8*)(B + (((wid * 2 + 0) * 8 + kk) * 64 + lane) * 8);
    d[3] = *(const bf16x8*)(B + (((wid * 2 + 1) * 8 + kk) * 64 + lane) * 8);
}
__device__ __forceinline__ void load_wl2(bf16x8& d0, bf16x8& d1,
                                         const short* Wlp, int kk, int wid, int lane) {
    d0 = *(const bf16x8*)(Wlp + (((wid * 2 + 0) * 5 + kk) * 64 + lane) * 8);
    d1 = *(const bf16x8*)(Wlp + (((wid * 2 + 1) * 5 + kk) * 64 + lane) * 8);
}

// ---------------------------------------------------------------------------
__global__ __launch_bounds__(512, 1) void rnn_kernel(
    const float* __restrict__ dense, const int* __restrict__ sparse,
    const int* __restrict__ lengths, const float* __restrict__ emb,
    const float* __restrict__ bl, const float* __restrict__ Wout,
    const float* __restrict__ bout, const short* __restrict__ wsS,
    const float* __restrict__ bsum, float* __restrict__ out) {
    __shared__ alignas(16) short sm[SM_TOT];
    short* xcat = sm + SM_XCAT;
    short* xpj  = sm + SM_XPJ;
    short* h0p  = sm + SM_H0;
    short* h1p  = sm + SM_H1;
    float* blS  = (float*)(sm + SM_BIAS);

    const int tid  = threadIdx.x;
    const int wid  = tid >> 6;
    const int lane = tid & 63;
    const int lrow = lane & 15;
    const int lgrp = lane >> 4;
    const int b0   = blockIdx.x * 32;
    const short* Wlp = wsS + WLP_OFF;

    for (int i = tid; i < SM_BIAS; i += 512) sm[i] = 0;
    for (int i = tid; i < 1280; i += 512)
        blS[i] = (i < 256) ? bl[i] : bsum[i - 256];

    const int len0 = lengths[b0 + lrow];
    const int len1 = lengths[b0 + 16 + lrow];

    __syncthreads();
    { GReg g0; gather_load(g0, dense, sparse, emb, b0, 0, tid); gather_commit(g0, xcat, tid); }
    __syncthreads();

    // xproj(0): direct-load version (runs once)
    {
        f32x4 xacc[2][2];
#pragma unroll
        for (int mt = 0; mt < 2; mt++) {
            f32x4 bi = *(const f32x4*)(blS + wid * 32 + mt * 16 + lgrp * 4);
            xacc[mt][0] = bi; xacc[mt][1] = bi;
        }
#pragma unroll
        for (int kk = 0; kk < 5; kk++) {
            bf16x8 wl0, wl1;
            load_wl2(wl0, wl1, Wlp, kk, wid, lane);
            bf16x8 bxf[2];
#pragma unroll
            for (int nt = 0; nt < 2; nt++)
                bxf[nt] = *(const bf16x8*)(xcat + (nt * 16 + lrow) * XCS + kk * 32 + lgrp * 8);
#pragma unroll
            for (int nt = 0; nt < 2; nt++) {
                xacc[0][nt] = MFMA(wl0, bxf[nt], xacc[0][nt]);
                xacc[1][nt] = MFMA(wl1, bxf[nt], xacc[1][nt]);
            }
        }
#pragma unroll
        for (int mt = 0; mt < 2; mt++) {
            int o0 = wid * 32 + mt * 16 + lgrp * 4;
#pragma unroll
            for (int nt = 0; nt < 2; nt++) {
                s16x4 w;
#pragma unroll
                for (int r = 0; r < 4; r++) w[r] = f2bf(fmaxf(xacc[mt][nt][r], 0.0f));
                *(s16x4*)(xpj + (nt * 16 + lrow) * HS + o0) = w;
            }
        }
    }

    bf16x8 wa[3][4];                // rolling weight window
    bf16x8 wnext[4];                // cross-phase prefetch buffer
    bf16x8 hreg0[2][8];             // h0(-1) = 0
    s16x4  h1def[2][2];             // deferred h1 values
#pragma unroll
    for (int nt = 0; nt < 2; nt++)
#pragma unroll
        for (int kk = 0; kk < 8; kk++) {
            bf16x8 z;
#pragma unroll
            for (int e = 0; e < 8; e++) z[e] = 0;
            hreg0[nt][kk] = z;
        }
#pragma unroll
    for (int mt = 0; mt < 2; mt++)
#pragma unroll
        for (int nt = 0; nt < 2; nt++) { s16x4 z; z[0]=z[1]=z[2]=z[3]=0; h1def[mt][nt] = z; }

    // preload P1(t=0, parity 0) chunks 0,1; then issue gather(t=1)
    load_c4(wa[0], wsS + WIHP_OFF, wsS + WHHP_OFF, 0, wid, lane);
    load_c4(wa[1], wsS + WIHP_OFF, wsS + WHHP_OFF, 1, wid, lane);
    GReg g;
    gather_load(g, dense, sparse, emb, b0, 1, tid);
    __syncthreads();               // xpj(0) visible

    f32x4 acc[2][2];

    for (int t = 0; t < T_; t++) {
        const int p = t & 1;
        const bool hasNext = (t + 1 < T_);
        const short* Aih1 = wsS + WIHP_OFF + p * 65536;
        const short* Ahh1 = wsS + WHHP_OFF + p * 65536;
        const short* Aih2 = wsS + WIHP_OFF + (2 + p) * 65536;
        const short* Ahh2 = wsS + WHHP_OFF + (2 + p) * 65536;
        const short* AihN = wsS + WIHP_OFF + (p ^ 1) * 65536;
        const short* AhhN = wsS + WHHP_OFF + (p ^ 1) * 65536;

        // deferred h1(t-1) LDS write (next reader = P2(t), after b1)
        if (t > 0) {
#pragma unroll
            for (int mt = 0; mt < 2; mt++) {
                int o0 = wid * 32 + mt * 16 + lgrp * 4;
#pragma unroll
                for (int nt = 0; nt < 2; nt++) {
                    int len = nt ? len1 : len0;
                    if (t - 1 < len)
                        *(s16x4*)(h1p + (nt * 16 + lrow) * HS + o0) = h1def[mt][nt];
                }
            }
        }

        // ================= P1: layer0(t) =================
        // reads wa[kk%3]; issues c(kk+2)->wa[(kk+2)%3] (kk<=5),
        // P2c0->wnext (kk==6), P2c1->wa[2] (kk==7).
#pragma unroll
        for (int mt = 0; mt < 2; mt++) {
            f32x4 bi = *(const f32x4*)(blS + 256 + p * 256 + wid * 32 + mt * 16 + lgrp * 4);
            acc[mt][0] = bi; acc[mt][1] = bi;
        }
#pragma unroll
        for (int kk = 0; kk < 8; kk++) {
            if (kk <= 5)      load_c4(wa[(kk + 2) % 3], Aih1, Ahh1, kk + 2, wid, lane);
            else if (kk == 6) load_c4(wnext, Aih2, Ahh2, 0, wid, lane);
            else              load_c4(wa[2], Aih2, Ahh2, 1, wid, lane);
            const int s = kk % 3;
            bf16x8 bxf[2];
#pragma unroll
            for (int nt = 0; nt < 2; nt++)
                bxf[nt] = *(const bf16x8*)(xpj + (nt * 16 + lrow) * HS + kk * 32 + lgrp * 8);
#pragma unroll
            for (int mt = 0; mt < 2; mt++)
#pragma unroll
                for (int nt = 0; nt < 2; nt++) {
                    acc[mt][nt] = MFMA(wa[s][mt], bxf[nt], acc[mt][nt]);
                    acc[mt][nt] = MFMA(wa[s][2 + mt], hreg0[nt][kk], acc[mt][nt]);
                }
        }
#pragma unroll
        for (int mt = 0; mt < 2; mt++) {        // in-place predicated h0 write
            int o0 = wid * 32 + mt * 16 + lgrp * 4;
#pragma unroll
            for (int nt = 0; nt < 2; nt++) {
                s16x4 w;
#pragma unroll
                for (int r = 0; r < 4; r++) w[r] = f2bf(tanh_fast(acc[mt][nt][r]));
                int len = nt ? len1 : len0;
                if (t < len)
                    *(s16x4*)(h0p + (nt * 16 + lrow) * HS + o0) = w;
            }
        }
        if (hasNext) gather_commit(g, xcat, tid);   // g issued at (t-1)'s A-tail
        __syncthreads();   // b1: h0(t), h1(t-1), xcat(t+1) visible

        // ================= P2: layer1(t) =================
        // reads: kk==0 -> wnext, kk>=1 -> wa[(kk+1)%3];
        // issues c(kk+2)->wa[kk%3] (kk<=5), WLc0/c1 -> wnext halves (kk=6,7).
#pragma unroll
        for (int mt = 0; mt < 2; mt++) {
            f32x4 bi = *(const f32x4*)(blS + 256 + (2 + p) * 256 + wid * 32 + mt * 16 + lgrp * 4);
            acc[mt][0] = bi; acc[mt][1] = bi;
        }
#pragma unroll
        for (int kk = 0; kk < 8; kk++) {
            if (kk <= 5)      load_c4(wa[kk % 3], Aih2, Ahh2, kk + 2, wid, lane);
            else if (kk == 6) { if (hasNext) load_wl2(wnext[0], wnext[1], Wlp, 0, wid, lane); }
            else              { if (hasNext) load_wl2(wnext[2], wnext[3], Wlp, 1, wid, lane); }
            bf16x8 bhf[2];
#pragma unroll
            for (int nt = 0; nt < 2; nt++) {    // fresh h0: ih operand + next P1 hh
                hreg0[nt][kk] = *(const bf16x8*)(h0p + (nt * 16 + lrow) * HS + kk * 32 + lgrp * 8);
                bhf[nt] = *(const bf16x8*)(h1p + (nt * 16 + lrow) * HS + kk * 32 + lgrp * 8);
            }
            if (kk == 0) {
#pragma unroll
                for (int mt = 0; mt < 2; mt++)
#pragma unroll
                    for (int nt = 0; nt < 2; nt++) {
                        acc[mt][nt] = MFMA(wnext[mt], hreg0[nt][0], acc[mt][nt]);
                        acc[mt][nt] = MFMA(wnext[2 + mt], bhf[nt], acc[mt][nt]);
                    }
            } else {
                const int s = (kk + 1) % 3;
#pragma unroll
                for (int mt = 0; mt < 2; mt++)
#pragma unroll
                    for (int nt = 0; nt < 2; nt++) {
                        acc[mt][nt] = MFMA(wa[s][mt], hreg0[nt][kk], acc[mt][nt]);
                        acc[mt][nt] = MFMA(wa[s][2 + mt], bhf[nt], acc[mt][nt]);
                    }
            }
        }
#pragma unroll
        for (int mt = 0; mt < 2; mt++)           // h1(t) -> registers (deferred)
#pragma unroll
            for (int nt = 0; nt < 2; nt++) {
                s16x4 w;
#pragma unroll
                for (int r = 0; r < 4; r++) w[r] = f2bf(tanh_fast(acc[mt][nt][r]));
                h1def[mt][nt] = w;
            }

        // ================= A: xproj(t+1) =================
        // reads: kk0->wnext[0,1], kk1->wnext[2,3], kk2..4->wa[kk-2][0,1];
        // issues WLc2..c4 -> wa[0..2][0,1] (kk=0..2), P1'c0->wa[0], c1->wa[1].
        if (hasNext) {
#pragma unroll
            for (int mt = 0; mt < 2; mt++) {
                f32x4 bi = *(const f32x4*)(blS + wid * 32 + mt * 16 + lgrp * 4);
                acc[mt][0] = bi; acc[mt][1] = bi;
            }
#pragma unroll
            for (int kk = 0; kk < 5; kk++) {
                if (kk <= 2)      load_wl2(wa[kk][0], wa[kk][1], Wlp, kk + 2, wid, lane);
                else if (kk == 3) load_c4(wa[0], AihN, AhhN, 0, wid, lane);
                else              load_c4(wa[1], AihN, AhhN, 1, wid, lane);
                bf16x8 w0, w1;
                if (kk == 0)      { w0 = wnext[0]; w1 = wnext[1]; }
                else if (kk == 1) { w0 = wnext[2]; w1 = wnext[3]; }
                else              { w0 = wa[kk - 2][0]; w1 = wa[kk - 2][1]; }
                bf16x8 bxf[2];
#pragma unroll
                for (int nt = 0; nt < 2; nt++)
                    bxf[nt] = *(const bf16x8*)(xcat + (nt * 16 + lrow) * XCS + kk * 32 + lgrp * 8);
#pragma unroll
                for (int nt = 0; nt < 2; nt++) {
                    acc[0][nt] = MFMA(w0, bxf[nt], acc[0][nt]);
                    acc[1][nt] = MFMA(w1, bxf[nt], acc[1][nt]);
                }
            }
#pragma unroll
            for (int mt = 0; mt < 2; mt++) {
                int o0 = wid * 32 + mt * 16 + lgrp * 4;
#pragma unroll
                for (int nt = 0; nt < 2; nt++) {
                    s16x4 w;
#pragma unroll
                    for (int r = 0; r < 4; r++) w[r] = f2bf(fmaxf(acc[mt][nt][r], 0.0f));
                    *(s16x4*)(xpj + (nt * 16 + lrow) * HS + o0) = w;
                }
            }
            if (t + 2 < T_)                       // gather for t+2, issued LAST
                gather_load(g, dense, sparse, emb, b0, t + 2, tid);
        }
        __syncthreads();   // b2: h1def pending; xpj(t+1) visible; prefetch in flight
    }

    // flush h1(T-1), then epilogue
#pragma unroll
    for (int mt = 0; mt < 2; mt++) {
        int o0 = wid * 32 + mt * 16 + lgrp * 4;
#pragma unroll
        for (int nt = 0; nt < 2; nt++) {
            int len = nt ? len1 : len0;
            if (T_ - 1 < len)
                *(s16x4*)(h1p + (nt * 16 + lrow) * HS + o0) = h1def[mt][nt];
        }
    }
    __syncthreads();

    // ---- epilogue: out = sigmoid(h1 . Wout + bout)
    float* red = (float*)(sm + SM_XPJ);
    if (tid < 256) {
        int s = tid >> 3, part = tid & 7;
        const short* hr = h1p + s * HS + part * 32;
        float sum = 0.0f;
#pragma unroll
        for (int k = 0; k < 32; k++) sum += bf2f(hr[k]) * Wout[part * 32 + k];
        red[s * 8 + part] = sum;
    }
    __syncthreads();
    if (tid < 32) {
        float x = bout[0];
#pragma unroll
        for (int i = 0; i < 8; i++) x += red[tid * 8 + i];
        float e = __builtin_amdgcn_exp2f(x * 1.44269504f);
        out[b0 + tid] = 1.0f - __builtin_amdgcn_rcpf(1.0f + e);
    }
}

// ---------------------------------------------------------------------------
extern "C" void kernel_launch(void* const* d_in, const int* in_sizes, int n_in,
                              void* d_out, int out_size, void* d_ws, size_t ws_size,
                              hipStream_t stream) {
    const float* dense   = (const float*)d_in[0];
    const int*   sparse  = (const int*)d_in[1];
    const int*   lengths = (const int*)d_in[2];
    const float* emb     = (const float*)d_in[3];
    const float* Wl      = (const float*)d_in[4];
    const float* bl      = (const float*)d_in[5];
    const float* Wih     = (const float*)d_in[6];
    const float* Whh     = (const float*)d_in[7];
    const float* bih     = (const float*)d_in[8];
    const float* bhh     = (const float*)d_in[9];
    const float* Wout    = (const float*)d_in[10];
    const float* bout    = (const float*)d_in[11];

    short* wsS  = (short*)d_ws;
    float* bsum = (float*)((char*)d_ws + BSUM_BYTE_OFF);

    prep_kernel<<<280, 256, 0, stream>>>(Wl, Wih, Whh, bih, bhh, wsS, bsum);
    rnn_kernel<<<256, 512, 0, stream>>>(dense, sparse, lengths, emb, bl, Wout, bout,
                                        wsS, bsum, (float*)d_out);
}

// Round 14
// 1156.193 us; speedup vs baseline: 3.8191x; 1.0884x over previous
//
#include <hip/hip_runtime.h>
#include <math.h>

// ---------------------------------------------------------------------------
// RNN_48558900248904. Round 14: RESTORE R10 verbatim — the verified optimum
// (1158us, VGPR 112, no spill, MfmaUtil 34.8%).
// Post-R10 attempts all regressed against measured constraints:
//   R11 (Wl->LDS): ds_read latency onto critical path, -118us.
//   R12 (step unroll): live ranges > 128-VGPR cap -> fatal spill, -3.3ms.
//   R13 (h1-defer): VGPR 112->128, scheduler lost prefetch depth, -100us.
// Structure: 256 WGs x 512 thr, 32 samples/WG, weights streamed global->VGPR
// via 3-slot rolling window + wnext cross-phase buffer; cross-phase issue
// cycle keeps 2-3 chunks + gather in flight across each barrier; gather for
// t+2 issued last (vmcnt in-order retirement). Wall ~13.9K cyc/step vs
// ~10.6K L2-ingest floor (73% of 34.5 TB/s aggregate) — at the practical
// streaming roofline for this op under the 128-VGPR allocator ceiling.
// ---------------------------------------------------------------------------

typedef __attribute__((ext_vector_type(8))) short bf16x8;   // 8 bf16 (4 VGPRs)
typedef __attribute__((ext_vector_type(4))) short s16x4;    // 8B store
typedef __attribute__((ext_vector_type(4))) float f32x4;

#define MFMA(a, b, c) __builtin_amdgcn_mfma_f32_16x16x32_bf16((a), (b), (c), 0, 0, 0)

#define T_  200

// ws layout (shorts)
#define WLP_OFF   0                       // Wl packed: ((mt*5+kk)*64+lane)*8
#define WIHP_OFF  40960                   // 4 mats x 65536
#define WHHP_OFF  (40960 + 262144)
#define BSUM_BYTE_OFF ((40960 + 262144 + 262144) * 2)   // then [2][2][256] f32

// LDS layout (shorts)
#define XCS 168
#define HS  264
#define SM_XCAT 0                         // [32][168] = 5376
#define SM_XPJ  5376                      // [32][264] = 8448 each
#define SM_H0   (SM_XPJ + 8448)
#define SM_H1A  (SM_H0 + 8448)
#define SM_H1B  (SM_H1A + 8448)
#define SM_BIAS (SM_H1B + 8448)          // 1280 f32 = 2560 shorts
#define SM_TOT  (SM_BIAS + 2560)         // 41984 shorts = 83968 B

__device__ __forceinline__ short f2bf(float f) {
    unsigned u = __float_as_uint(f);
    u += 0x7fffu + ((u >> 16) & 1u);      // RNE
    return (short)(u >> 16);
}
__device__ __forceinline__ float bf2f(short s) {
    return __uint_as_float(((unsigned)(unsigned short)s) << 16);
}
__device__ __forceinline__ float tanh_fast(float x) {
    float e = __builtin_amdgcn_exp2f(x * 2.88539008f);
    return 1.0f - 2.0f * __builtin_amdgcn_rcpf(e + 1.0f);
}

// ---------------------------------------------------------------------------
__global__ void prep_kernel(const float* __restrict__ Wl,
                            const float* __restrict__ Wih,
                            const float* __restrict__ Whh,
                            const float* __restrict__ bih,
                            const float* __restrict__ bhh,
                            short* __restrict__ wsS,
                            float* __restrict__ bsum) {
    int tid = blockIdx.x * 256 + threadIdx.x;
    if (tid < 5120) {                       // Wl pack (K padded 136 -> 160)
        int mt = tid / 320, rem = tid % 320;
        int kk = rem / 64, lane = rem % 64;
        int o = mt * 16 + (lane & 15);
        int kb = kk * 32 + (lane >> 4) * 8;
        short* dst = wsS + WLP_OFF + tid * 8;
#pragma unroll
        for (int e = 0; e < 8; e++) {
            int k = kb + e;
            dst[e] = f2bf((k < 136) ? Wl[o * 136 + k] : 0.0f);
        }
    } else if (tid < 5120 + 32768) {        // Wih pack
        int jj = tid - 5120;
        int mat = jj / 8192, rem = jj % 8192;
        int lane = rem & 63, kk = (rem >> 6) & 7, mt = rem >> 9;
        int o = mt * 16 + (lane & 15);
        int kb = kk * 32 + (lane >> 4) * 8;
        const float* src = Wih + (mat * 256 + o) * 256;
        short* dst = wsS + WIHP_OFF + mat * 65536 + rem * 8;
#pragma unroll
        for (int e = 0; e < 8; e++) dst[e] = f2bf(src[kb + e]);
    } else if (tid < 5120 + 65536) {        // Whh pack
        int jj = tid - 37888;
        int mat = jj / 8192, rem = jj % 8192;
        int lane = rem & 63, kk = (rem >> 6) & 7, mt = rem >> 9;
        int o = mt * 16 + (lane & 15);
        int kb = kk * 32 + (lane >> 4) * 8;
        const float* src = Whh + (mat * 256 + o) * 256;
        short* dst = wsS + WHHP_OFF + mat * 65536 + rem * 8;
#pragma unroll
        for (int e = 0; e < 8; e++) dst[e] = f2bf(src[kb + e]);
    } else if (tid < 5120 + 65536 + 1024) { // bsum = bih + bhh
        int j = tid - 70656;
        bsum[j] = bih[j] + bhh[j];
    }
}

// ---------------------------------------------------------------------------
struct GReg { f32x4 e0, e1, dv; };

__device__ __forceinline__ void gather_load(GReg& g, const float* __restrict__ dense,
                                            const int* __restrict__ sparse,
                                            const float* __restrict__ emb,
                                            int b0, int tt, int tid) {
    int gs = tid >> 4, gf = (tid >> 2) & 3, gq = tid & 3;
    int ix = sparse[(b0 + gs) * (T_ * 4) + tt * 4 + gf];
    const float* ep = emb + gf * 32000 + ix * 32 + gq * 8;
    g.e0 = *(const f32x4*)ep;
    g.e1 = *(const f32x4*)(ep + 4);
    if (tid < 64)
        g.dv = *(const f32x4*)(dense + (b0 + (tid >> 1)) * (T_ * 8) + tt * 8 + (tid & 1) * 4);
}
__device__ __forceinline__ void gather_commit(const GReg& g, short* __restrict__ buf, int tid) {
    int gs = tid >> 4, gf = (tid >> 2) & 3, gq = tid & 3;
    s16x4 w0, w1;
#pragma unroll
    for (int r = 0; r < 4; r++) { w0[r] = f2bf(g.e0[r]); w1[r] = f2bf(g.e1[r]); }
    int off = gs * XCS + 8 + gf * 32 + gq * 8;
    *(s16x4*)(buf + off) = w0;
    *(s16x4*)(buf + off + 4) = w1;
    if (tid < 64) {
        s16x4 wd;
#pragma unroll
        for (int r = 0; r < 4; r++) wd[r] = f2bf(g.dv[r]);
        *(s16x4*)(buf + (tid >> 1) * XCS + (tid & 1) * 4) = wd;
    }
}

// weight chunk loaders (slot indices constant after unroll -> registers)
__device__ __forceinline__ void load_c4(bf16x8 (&d)[4], const short* A, const short* B,
                                        int kk, int wid, int lane) {
    d[0] = *(const bf16x8*)(A + (((wid * 2 + 0) * 8 + kk) * 64 + lane) * 8);
    d[1] = *(const bf16x8*)(A + (((wid * 2 + 1) * 8 + kk) * 64 + lane) * 8);
    d[2] = *(const bf16x8*)(B + (((wid * 2 + 0) * 8 + kk) * 64 + lane) * 8);
    d[3] = *(const bf16x8*)(B + (((wid * 2 + 1) * 8 + kk) * 64 + lane) * 8);
}
__device__ __forceinline__ void load_wl2(bf16x8& d0, bf16x8& d1,
                                         const short* Wlp, int kk, int wid, int lane) {
    d0 = *(const bf16x8*)(Wlp + (((wid * 2 + 0) * 5 + kk) * 64 + lane) * 8);
    d1 = *(const bf16x8*)(Wlp + (((wid * 2 + 1) * 5 + kk) * 64 + lane) * 8);
}

// ---------------------------------------------------------------------------
__global__ __launch_bounds__(512, 1) void rnn_kernel(
    const float* __restrict__ dense, const int* __restrict__ sparse,
    const int* __restrict__ lengths, const float* __restrict__ emb,
    const float* __restrict__ bl, const float* __restrict__ Wout,
    const float* __restrict__ bout, const short* __restrict__ wsS,
    const float* __restrict__ bsum, float* __restrict__ out) {
    __shared__ alignas(16) short sm[SM_TOT];
    short* xcat = sm + SM_XCAT;
    short* xpj  = sm + SM_XPJ;
    short* h0p  = sm + SM_H0;
    short* h1a  = sm + SM_H1A;
    short* h1b  = sm + SM_H1B;
    float* blS  = (float*)(sm + SM_BIAS);

    const int tid  = threadIdx.x;
    const int wid  = tid >> 6;
    const int lane = tid & 63;
    const int lrow = lane & 15;
    const int lgrp = lane >> 4;
    const int b0   = blockIdx.x * 32;
    const short* Wlp = wsS + WLP_OFF;

    for (int i = tid; i < SM_BIAS; i += 512) sm[i] = 0;
    for (int i = tid; i < 1280; i += 512)
        blS[i] = (i < 256) ? bl[i] : bsum[i - 256];

    const int len0 = lengths[b0 + lrow];
    const int len1 = lengths[b0 + 16 + lrow];

    __syncthreads();
    { GReg g0; gather_load(g0, dense, sparse, emb, b0, 0, tid); gather_commit(g0, xcat, tid); }
    __syncthreads();

    // xproj(0): direct-load version (runs once)
    {
        f32x4 xacc[2][2];
#pragma unroll
        for (int mt = 0; mt < 2; mt++) {
            f32x4 bi = *(const f32x4*)(blS + wid * 32 + mt * 16 + lgrp * 4);
            xacc[mt][0] = bi; xacc[mt][1] = bi;
        }
#pragma unroll
        for (int kk = 0; kk < 5; kk++) {
            bf16x8 wl0, wl1;
            load_wl2(wl0, wl1, Wlp, kk, wid, lane);
            bf16x8 bxf[2];
#pragma unroll
            for (int nt = 0; nt < 2; nt++)
                bxf[nt] = *(const bf16x8*)(xcat + (nt * 16 + lrow) * XCS + kk * 32 + lgrp * 8);
#pragma unroll
            for (int nt = 0; nt < 2; nt++) {
                xacc[0][nt] = MFMA(wl0, bxf[nt], xacc[0][nt]);
                xacc[1][nt] = MFMA(wl1, bxf[nt], xacc[1][nt]);
            }
        }
#pragma unroll
        for (int mt = 0; mt < 2; mt++) {
            int o0 = wid * 32 + mt * 16 + lgrp * 4;
#pragma unroll
            for (int nt = 0; nt < 2; nt++) {
                s16x4 w;
#pragma unroll
                for (int r = 0; r < 4; r++) w[r] = f2bf(fmaxf(xacc[mt][nt][r], 0.0f));
                *(s16x4*)(xpj + (nt * 16 + lrow) * HS + o0) = w;
            }
        }
    }

    bf16x8 wa[3][4];                // rolling weight window
    bf16x8 wnext[4];                // cross-phase prefetch buffer
    bf16x8 hreg0[2][8];             // h0(-1) = 0
#pragma unroll
    for (int nt = 0; nt < 2; nt++)
#pragma unroll
        for (int kk = 0; kk < 8; kk++) {
            bf16x8 z;
#pragma unroll
            for (int e = 0; e < 8; e++) z[e] = 0;
            hreg0[nt][kk] = z;
        }

    // preload P1(t=0, parity 0) chunks 0,1; then issue gather(t=1)
    load_c4(wa[0], wsS + WIHP_OFF, wsS + WHHP_OFF, 0, wid, lane);
    load_c4(wa[1], wsS + WIHP_OFF, wsS + WHHP_OFF, 1, wid, lane);
    GReg g;
    gather_load(g, dense, sparse, emb, b0, 1, tid);
    __syncthreads();               // xpj(0) visible

    f32x4 acc[2][2];

    for (int t = 0; t < T_; t++) {
        const int p = t & 1;
        const bool hasNext = (t + 1 < T_);
        const short* Aih1 = wsS + WIHP_OFF + p * 65536;
        const short* Ahh1 = wsS + WHHP_OFF + p * 65536;
        const short* Aih2 = wsS + WIHP_OFF + (2 + p) * 65536;
        const short* Ahh2 = wsS + WHHP_OFF + (2 + p) * 65536;
        const short* AihN = wsS + WIHP_OFF + (p ^ 1) * 65536;
        const short* AhhN = wsS + WHHP_OFF + (p ^ 1) * 65536;

        // ================= P1: layer0(t) =================
        // reads wa[kk%3]; issues c(kk+2)->wa[(kk+2)%3] (kk<=5),
        // P2c0->wnext (kk==6), P2c1->wa[2] (kk==7).
#pragma unroll
        for (int mt = 0; mt < 2; mt++) {
            f32x4 bi = *(const f32x4*)(blS + 256 + p * 256 + wid * 32 + mt * 16 + lgrp * 4);
            acc[mt][0] = bi; acc[mt][1] = bi;
        }
#pragma unroll
        for (int kk = 0; kk < 8; kk++) {
            if (kk <= 5)      load_c4(wa[(kk + 2) % 3], Aih1, Ahh1, kk + 2, wid, lane);
            else if (kk == 6) load_c4(wnext, Aih2, Ahh2, 0, wid, lane);
            else              load_c4(wa[2], Aih2, Ahh2, 1, wid, lane);
            const int s = kk % 3;
            bf16x8 bxf[2];
#pragma unroll
            for (int nt = 0; nt < 2; nt++)
                bxf[nt] = *(const bf16x8*)(xpj + (nt * 16 + lrow) * HS + kk * 32 + lgrp * 8);
#pragma unroll
            for (int mt = 0; mt < 2; mt++)
#pragma unroll
                for (int nt = 0; nt < 2; nt++) {
                    acc[mt][nt] = MFMA(wa[s][mt], bxf[nt], acc[mt][nt]);
                    acc[mt][nt] = MFMA(wa[s][2 + mt], hreg0[nt][kk], acc[mt][nt]);
                }
        }
#pragma unroll
        for (int mt = 0; mt < 2; mt++) {        // in-place predicated h0 write
            int o0 = wid * 32 + mt * 16 + lgrp * 4;
#pragma unroll
            for (int nt = 0; nt < 2; nt++) {
                s16x4 w;
#pragma unroll
                for (int r = 0; r < 4; r++) w[r] = f2bf(tanh_fast(acc[mt][nt][r]));
                int len = nt ? len1 : len0;
                if (t < len)
                    *(s16x4*)(h0p + (nt * 16 + lrow) * HS + o0) = w;
            }
        }
        if (hasNext) gather_commit(g, xcat, tid);   // g issued at (t-1)'s A-tail
        __syncthreads();   // b1: h0(t), xcat(t+1) visible

        // ================= P2: layer1(t) =================
        // reads: kk==0 -> wnext, kk>=1 -> wa[(kk+1)%3];
        // issues c(kk+2)->wa[kk%3] (kk<=5), WLc0/c1 -> wnext halves (kk=6,7).
        const short* h1r = p ? h1b : h1a;
        short* h1w = p ? h1a : h1b;
#pragma unroll
        for (int mt = 0; mt < 2; mt++) {
            f32x4 bi = *(const f32x4*)(blS + 256 + (2 + p) * 256 + wid * 32 + mt * 16 + lgrp * 4);
            acc[mt][0] = bi; acc[mt][1] = bi;
        }
#pragma unroll
        for (int kk = 0; kk < 8; kk++) {
            if (kk <= 5)      load_c4(wa[kk % 3], Aih2, Ahh2, kk + 2, wid, lane);
            else if (kk == 6) { if (hasNext) load_wl2(wnext[0], wnext[1], Wlp, 0, wid, lane); }
            else              { if (hasNext) load_wl2(wnext[2], wnext[3], Wlp, 1, wid, lane); }
            bf16x8 bhf[2];
#pragma unroll
            for (int nt = 0; nt < 2; nt++) {    // fresh h0: ih operand + next P1 hh
                hreg0[nt][kk] = *(const bf16x8*)(h0p + (nt * 16 + lrow) * HS + kk * 32 + lgrp * 8);
                bhf[nt] = *(const bf16x8*)(h1r + (nt * 16 + lrow) * HS + kk * 32 + lgrp * 8);
            }
            if (kk == 0) {
#pragma unroll
                for (int mt = 0; mt < 2; mt++)
#pragma unroll
                    for (int nt = 0; nt < 2; nt++) {
                        acc[mt][nt] = MFMA(wnext[mt], hreg0[nt][0], acc[mt][nt]);
                        acc[mt][nt] = MFMA(wnext[2 + mt], bhf[nt], acc[mt][nt]);
                    }
            } else {
                const int s = (kk + 1) % 3;
#pragma unroll
                for (int mt = 0; mt < 2; mt++)
#pragma unroll
                    for (int nt = 0; nt < 2; nt++) {
                        acc[mt][nt] = MFMA(wa[s][mt], hreg0[nt][kk], acc[mt][nt]);
                        acc[mt][nt] = MFMA(wa[s][2 + mt], bhf[nt], acc[mt][nt]);
                    }
            }
        }
#pragma unroll
        for (int mt = 0; mt < 2; mt++) {         // h1 ping-pong select-freeze
            int o0 = wid * 32 + mt * 16 + lgrp * 4;
#pragma unroll
            for (int nt = 0; nt < 2; nt++) {
                int roff = (nt * 16 + lrow) * HS + o0;
                s16x4 oldv = *(const s16x4*)(h1r + roff);
                s16x4 w;
#pragma unroll
                for (int r = 0; r < 4; r++) w[r] = f2bf(tanh_fast(acc[mt][nt][r]));
                int len = nt ? len1 : len0;
                *(s16x4*)(h1w + roff) = (t < len) ? w : oldv;
            }
        }

        // ================= A: xproj(t+1) =================
        // reads: kk0->wnext[0,1], kk1->wnext[2,3], kk2..4->wa[kk-2][0,1];
        // issues WLc2..c4 -> wa[0..2][0,1] (kk=0..2), P1'c0->wa[0], c1->wa[1].
        if (hasNext) {
#pragma unroll
            for (int mt = 0; mt < 2; mt++) {
                f32x4 bi = *(const f32x4*)(blS + wid * 32 + mt * 16 + lgrp * 4);
                acc[mt][0] = bi; acc[mt][1] = bi;
            }
#pragma unroll
            for (int kk = 0; kk < 5; kk++) {
                if (kk <= 2)      load_wl2(wa[kk][0], wa[kk][1], Wlp, kk + 2, wid, lane);
                else if (kk == 3) load_c4(wa[0], AihN, AhhN, 0, wid, lane);
                else              load_c4(wa[1], AihN, AhhN, 1, wid, lane);
                bf16x8 w0, w1;
                if (kk == 0)      { w0 = wnext[0]; w1 = wnext[1]; }
                else if (kk == 1) { w0 = wnext[2]; w1 = wnext[3]; }
                else              { w0 = wa[kk - 2][0]; w1 = wa[kk - 2][1]; }
                bf16x8 bxf[2];
#pragma unroll
                for (int nt = 0; nt < 2; nt++)
                    bxf[nt] = *(const bf16x8*)(xcat + (nt * 16 + lrow) * XCS + kk * 32 + lgrp * 8);
#pragma unroll
                for (int nt = 0; nt < 2; nt++) {
                    acc[0][nt] = MFMA(w0, bxf[nt], acc[0][nt]);
                    acc[1][nt] = MFMA(w1, bxf[nt], acc[1][nt]);
                }
            }
#pragma unroll
            for (int mt = 0; mt < 2; mt++) {
                int o0 = wid * 32 + mt * 16 + lgrp * 4;
#pragma unroll
                for (int nt = 0; nt < 2; nt++) {
                    s16x4 w;
#pragma unroll
                    for (int r = 0; r < 4; r++) w[r] = f2bf(fmaxf(acc[mt][nt][r], 0.0f));
                    *(s16x4*)(xpj + (nt * 16 + lrow) * HS + o0) = w;
                }
            }
            if (t + 2 < T_)                       // gather for t+2, issued LAST
                gather_load(g, dense, sparse, emb, b0, t + 2, tid);
        }
        __syncthreads();   // b2: h1(t), xpj(t+1) visible; prefetches in flight
    }

    // ---- epilogue: out = sigmoid(h1 . Wout + bout); final h1 = h1a (T even)
    float* red = (float*)(sm + SM_XPJ);
    if (tid < 256) {
        int s = tid >> 3, part = tid & 7;
        const short* hr = h1a + s * HS + part * 32;
        float sum = 0.0f;
#pragma unroll
        for (int k = 0; k < 32; k++) sum += bf2f(hr[k]) * Wout[part * 32 + k];
        red[s * 8 + part] = sum;
    }
    __syncthreads();
    if (tid < 32) {
        float x = bout[0];
#pragma unroll
        for (int i = 0; i < 8; i++) x += red[tid * 8 + i];
        float e = __builtin_amdgcn_exp2f(x * 1.44269504f);
        out[b0 + tid] = 1.0f - __builtin_amdgcn_rcpf(1.0f + e);
    }
}

// ---------------------------------------------------------------------------
extern "C" void kernel_launch(void* const* d_in, const int* in_sizes, int n_in,
                              void* d_out, int out_size, void* d_ws, size_t ws_size,
                              hipStream_t stream) {
    const float* dense   = (const float*)d_in[0];
    const int*   sparse  = (const int*)d_in[1];
    const int*   lengths = (const int*)d_in[2];
    const float* emb     = (const float*)d_in[3];
    const float* Wl      = (const float*)d_in[4];
    const float* bl      = (const float*)d_in[5];
    const float* Wih     = (const float*)d_in[6];
    const float* Whh     = (const float*)d_in[7];
    const float* bih     = (const float*)d_in[8];
    const float* bhh     = (const float*)d_in[9];
    const float* Wout    = (const float*)d_in[10];
    const float* bout    = (const float*)d_in[11];

    short* wsS  = (short*)d_ws;
    float* bsum = (float*)((char*)d_ws + BSUM_BYTE_OFF);

    prep_kernel<<<280, 256, 0, stream>>>(Wl, Wih, Whh, bih, bhh, wsS, bsum);
    rnn_kernel<<<256, 512, 0, stream>>>(dense, sparse, lengths, emb, bl, Wout, bout,
                                        wsS, bsum, (float*)d_out);
}